// Round 1
// baseline (4029.120 us; speedup 1.0000x reference)
//
#include <hip/hip_runtime.h>
#include <stdint.h>
#include <stddef.h>

// ---------------- problem constants ----------------
#define T_TOT   5152            // DOFF + DECODE
#define T_PAD   5248            // 41 * 128
#define D_OFF   5120
#define N_DEC   32
#define PASTLEN 2048
#define HID     4096
#define NQH     32
#define NKVH    8
#define HDIM    128
#define SCALE_F 0.088388347648318447f   // 1/sqrt(128)

typedef unsigned short u16;
typedef __attribute__((ext_vector_type(8))) short bf16x8;   // 8 bf16 = 4 VGPRs (MFMA A/B frag)
typedef __attribute__((ext_vector_type(4))) float f32x4;    // MFMA C/D frag

#define MFMA16(a, b, c) __builtin_amdgcn_mfma_f32_16x16x32_bf16((a), (b), (c), 0, 0, 0)

__device__ __forceinline__ float bf2f(u16 h) { return __uint_as_float(((unsigned)h) << 16); }
__device__ __forceinline__ u16 f2bf(float f) {
  unsigned u = __float_as_uint(f);
  return (u16)((u + 0x7FFFu + ((u >> 16) & 1u)) >> 16);   // RNE
}

// ---------------- cast kernels ----------------
// hidden [T_TOT][HID] fp32 -> [T_PAD][HID] bf16, zero-filled pad rows
__global__ void cast_pad_hidden(const float* __restrict__ src, u16* __restrict__ dst) {
  long idx = ((long)blockIdx.x * 256 + threadIdx.x) * 8;
  int row = (int)(idx >> 12);
  __align__(16) u16 tmp[8];
  if (row < T_TOT) {
    const float4* s = (const float4*)(src + (size_t)row * HID + (idx & 4095));
    float4 a = s[0], b = s[1];
    tmp[0] = f2bf(a.x); tmp[1] = f2bf(a.y); tmp[2] = f2bf(a.z); tmp[3] = f2bf(a.w);
    tmp[4] = f2bf(b.x); tmp[5] = f2bf(b.y); tmp[6] = f2bf(b.z); tmp[7] = f2bf(b.w);
  } else {
#pragma unroll
    for (int j = 0; j < 8; ++j) tmp[j] = 0;
  }
  *(uint4*)(dst + idx) = *(const uint4*)tmp;
}

__global__ void cast_w(const float* __restrict__ src, u16* __restrict__ dst, int n8) {
  int i = blockIdx.x * 256 + threadIdx.x;
  if (i >= n8) return;
  long idx = (long)i * 8;
  const float4* s = (const float4*)(src + idx);
  float4 a = s[0], b = s[1];
  __align__(16) u16 tmp[8];
  tmp[0] = f2bf(a.x); tmp[1] = f2bf(a.y); tmp[2] = f2bf(a.z); tmp[3] = f2bf(a.w);
  tmp[4] = f2bf(b.x); tmp[5] = f2bf(b.y); tmp[6] = f2bf(b.z); tmp[7] = f2bf(b.w);
  *(uint4*)(dst + idx) = *(const uint4*)tmp;
}

// ---------------- RoPE ----------------
// cos/sin table for pos 0..2048, i 0..63 (inv_freq = 10000^(-i/64))
__global__ void rope_table(float* __restrict__ tcos, float* __restrict__ tsin) {
  int p = blockIdx.x;        // 0..2048
  int i = threadIdx.x;       // 0..63
  float inv = powf(10000.0f, -((float)i) / 64.0f);
  float ang = (float)p * inv;
  tcos[p * 64 + i] = cosf(ang);
  tsin[p * 64 + i] = sinf(ang);
}

// in-place RoPE on q (32 heads) and k (8 heads); prefill rows use seq-local pos, decode rows pos=2048
__global__ void rope_apply(u16* __restrict__ qb, u16* __restrict__ kb,
                           const float* __restrict__ tcos, const float* __restrict__ tsin) {
  int row = blockIdx.x;      // 0..T_TOT-1
  int pos;
  if (row >= D_OFF)      pos = PASTLEN;
  else if (row >= 4608)  pos = row - 4608;
  else if (row >= 2560)  pos = row - 2560;
  else if (row >= 1024)  pos = row - 1024;
  else                   pos = row;
  const float* tc = tcos + (size_t)pos * 64;
  const float* ts = tsin + (size_t)pos * 64;
  for (int it = threadIdx.x; it < (NQH + NKVH) * 64; it += 256) {
    int h = it >> 6, i = it & 63;
    u16* base;
    if (h < NQH) base = qb + (size_t)row * HID + h * HDIM + i;
    else         base = kb + (size_t)row * (NKVH * HDIM) + (h - NQH) * HDIM + i;
    float x0 = bf2f(base[0]), x1 = bf2f(base[64]);
    float c = tc[i], s = ts[i];
    base[0]  = f2bf(x0 * c - x1 * s);
    base[64] = f2bf(x1 * c + x0 * s);
  }
}

// ---------------- GEMM: C[M][N] = A[M][K] * B[N][K]^T  (both bf16, K-major) ----------------
// 128x128 tile, BK=64, 256 threads = 4 waves (2x2), 4x4 16x16x32 MFMAs per wave.
__device__ __forceinline__ void store_c(u16* p, float v)   { *p = f2bf(v); }
__device__ __forceinline__ void store_c(float* p, float v) { *p = v; }

template <typename OutT>
__global__ __launch_bounds__(256) void gemm_bt(const u16* __restrict__ A, const u16* __restrict__ B,
                                               OutT* __restrict__ C, int N, int K, int Mstore) {
  __shared__ u16 As[128 * 64];
  __shared__ u16 Bs[128 * 64];
  const int tid = threadIdx.x;
  const int lane = tid & 63, wave = tid >> 6;
  const int wm = wave >> 1, wn = wave & 1;
  const int m = lane & 15, q4 = lane >> 4;
  const long by = blockIdx.y, bx = blockIdx.x;

  f32x4 acc[4][4];
#pragma unroll
  for (int i = 0; i < 4; ++i)
#pragma unroll
    for (int j = 0; j < 4; ++j) acc[i][j] = (f32x4){0.f, 0.f, 0.f, 0.f};

  int rowA[4], colc[4];
#pragma unroll
  for (int p = 0; p < 4; ++p) {
    int cid = p * 256 + tid;
    rowA[p] = cid >> 3;          // 0..127
    colc[p] = (cid & 7) * 8;     // element offset of 16B chunk in the 64-wide k-slice
  }

  uint4 ga[4], gb[4];
  const int nk = K / 64;
  // prefetch kt=0
#pragma unroll
  for (int p = 0; p < 4; ++p) {
    ga[p] = *(const uint4*)(A + (by * 128 + rowA[p]) * (size_t)K + colc[p]);
    gb[p] = *(const uint4*)(B + (bx * 128 + rowA[p]) * (size_t)K + colc[p]);
  }

  for (int kt = 0; kt < nk; ++kt) {
    __syncthreads();
#pragma unroll
    for (int p = 0; p < 4; ++p) {
      int r = rowA[p], c = colc[p] >> 3;
      *(uint4*)(As + r * 64 + ((c ^ (r & 7)) << 3)) = ga[p];   // XOR-swizzled chunks
      *(uint4*)(Bs + r * 64 + ((c ^ (r & 7)) << 3)) = gb[p];
    }
    __syncthreads();
    if (kt + 1 < nk) {
      size_t k0 = (size_t)(kt + 1) * 64;
#pragma unroll
      for (int p = 0; p < 4; ++p) {
        ga[p] = *(const uint4*)(A + (by * 128 + rowA[p]) * (size_t)K + k0 + colc[p]);
        gb[p] = *(const uint4*)(B + (bx * 128 + rowA[p]) * (size_t)K + k0 + colc[p]);
      }
    }
#pragma unroll
    for (int ks = 0; ks < 2; ++ks) {
      bf16x8 af[4], bfr[4];
#pragma unroll
      for (int mt = 0; mt < 4; ++mt) {
        int r = wm * 64 + mt * 16 + m;
        int ch = (ks * 4 + q4) ^ (r & 7);
        af[mt] = *(const bf16x8*)(As + r * 64 + (ch << 3));
      }
#pragma unroll
      for (int nt = 0; nt < 4; ++nt) {
        int r = wn * 64 + nt * 16 + m;
        int ch = (ks * 4 + q4) ^ (r & 7);
        bfr[nt] = *(const bf16x8*)(Bs + r * 64 + (ch << 3));
      }
#pragma unroll
      for (int mt = 0; mt < 4; ++mt)
#pragma unroll
        for (int nt = 0; nt < 4; ++nt)
          acc[mt][nt] = MFMA16(af[mt], bfr[nt], acc[mt][nt]);
    }
  }

  // epilogue: C/D layout col = lane&15, row = quad*4 + reg
#pragma unroll
  for (int mt = 0; mt < 4; ++mt)
#pragma unroll
    for (int nt = 0; nt < 4; ++nt) {
      int row0 = (int)by * 128 + wm * 64 + mt * 16 + q4 * 4;
      int col = (int)bx * 128 + wn * 64 + nt * 16 + m;
#pragma unroll
      for (int r = 0; r < 4; ++r) {
        int row = row0 + r;
        if (row < Mstore) store_c(C + (size_t)row * N + col, acc[mt][nt][r]);
      }
    }
}

// ---------------- flash prefill attention ----------------
// grid: x = global q-tile (40 tiles of 128 rows), y = q head (32).
// Per block: Q-tile 128 x 128, iterate 64-key tiles causally; 4 waves each own 32 q-rows.
__global__ __launch_bounds__(256) void flash_prefill(const u16* __restrict__ qb,
                                                     const u16* __restrict__ kb,
                                                     const u16* __restrict__ vb,
                                                     u16* __restrict__ attn) {
  const int gq = blockIdx.x;
  const int n = blockIdx.y;
  int qtl, soff;
  if (gq < 8)       { qtl = gq;      soff = 0; }
  else if (gq < 20) { qtl = gq - 8;  soff = 1024; }
  else if (gq < 36) { qtl = gq - 20; soff = 2560; }
  else              { qtl = gq - 36; soff = 4608; }
  const int kvh = n >> 2;
  const int tid = threadIdx.x;
  const int lane = tid & 63;
  const int w = tid >> 6;
  const int m = lane & 15, q4 = lane >> 4;

  __shared__ u16 Ks[64 * 128];     // [t][d], d XOR-swizzled in 8-elem chunks
  __shared__ u16 Vt[128 * 72];     // [d][t], padded stride 72
  __shared__ u16 Pl[4 * 32 * 72];  // per-wave P [32 qr][64 t], stride 72

  // Q A-frags: wave w owns q-rows [32w, 32w+32)
  bf16x8 aq[2][4];
#pragma unroll
  for (int mt = 0; mt < 2; ++mt)
#pragma unroll
    for (int ks = 0; ks < 4; ++ks) {
      int row = soff + qtl * 128 + w * 32 + mt * 16 + m;
      aq[mt][ks] = *(const bf16x8*)(qb + (size_t)row * HID + n * HDIM + ks * 32 + q4 * 8);
    }

  f32x4 O[2][8];
#pragma unroll
  for (int mt = 0; mt < 2; ++mt)
#pragma unroll
    for (int nd = 0; nd < 8; ++nd) O[mt][nd] = (f32x4){0.f, 0.f, 0.f, 0.f};
  float mst[2][4], lst[2][4];
#pragma unroll
  for (int mt = 0; mt < 2; ++mt)
#pragma unroll
    for (int r = 0; r < 4; ++r) { mst[mt][r] = -3.0e38f; lst[mt][r] = 0.f; }

  const int st_t = tid & 63;       // staging: lane -> key row
  const int st_c = tid >> 6;       // staging: wave -> chunk
  const int ktmax = 2 * qtl + 1;

  for (int kt = 0; kt <= ktmax; ++kt) {
    __syncthreads();
    {
      const int koff = soff + kt * 64;
      const size_t gbase = (size_t)(koff + st_t) * (NKVH * HDIM) + kvh * HDIM;
#pragma unroll
      for (int p = 0; p < 4; ++p) {
        int c = st_c + p * 4;      // 0..15
        uint4 kv_ = *(const uint4*)(kb + gbase + c * 8);
        *(uint4*)(Ks + st_t * 128 + ((c ^ (st_t & 7)) << 3)) = kv_;
        union { uint4 u; u16 s[8]; } uv;
        uv.u = *(const uint4*)(vb + gbase + c * 8);
#pragma unroll
        for (int j = 0; j < 8; ++j) Vt[(c * 8 + j) * 72 + st_t] = uv.s[j];  // transpose, stride-1 writes
      }
    }
    __syncthreads();

    bool skip = (kt == 2 * qtl + 1) && (w < 2);   // fully-masked waves in the last tile
    if (!skip) {
      // S = Q K^T : 32 MFMAs
      f32x4 S[2][4];
#pragma unroll
      for (int mt = 0; mt < 2; ++mt)
#pragma unroll
        for (int nt = 0; nt < 4; ++nt) S[mt][nt] = (f32x4){0.f, 0.f, 0.f, 0.f};
#pragma unroll
      for (int ks = 0; ks < 4; ++ks) {
        bf16x8 bk[4];
#pragma unroll
        for (int nt = 0; nt < 4; ++nt) {
          int tr = nt * 16 + m;
          int ch = (ks * 4 + q4) ^ (tr & 7);
          bk[nt] = *(const bf16x8*)(Ks + tr * 128 + (ch << 3));
        }
#pragma unroll
        for (int mt = 0; mt < 2; ++mt)
#pragma unroll
          for (int nt = 0; nt < 4; ++nt)
            S[mt][nt] = MFMA16(aq[mt][ks], bk[nt], S[mt][nt]);
      }
      // scale + causal mask
#pragma unroll
      for (int mt = 0; mt < 2; ++mt)
#pragma unroll
        for (int nt = 0; nt < 4; ++nt)
#pragma unroll
          for (int r = 0; r < 4; ++r) S[mt][nt][r] *= SCALE_F;
      if (kt >= 2 * qtl) {
#pragma unroll
        for (int mt = 0; mt < 2; ++mt)
#pragma unroll
          for (int nt = 0; nt < 4; ++nt)
#pragma unroll
            for (int r = 0; r < 4; ++r) {
              int key = kt * 64 + nt * 16 + m;
              int qp = qtl * 128 + w * 32 + mt * 16 + q4 * 4 + r;
              if (key > qp) S[mt][nt][r] = -1.0e30f;
            }
      }
      // online softmax (row stats via 16-lane quad shuffles)
      float al[2][4];
#pragma unroll
      for (int mt = 0; mt < 2; ++mt)
#pragma unroll
        for (int r = 0; r < 4; ++r) {
          float v = fmaxf(fmaxf(S[mt][0][r], S[mt][1][r]), fmaxf(S[mt][2][r], S[mt][3][r]));
          v = fmaxf(v, __shfl_xor(v, 1));
          v = fmaxf(v, __shfl_xor(v, 2));
          v = fmaxf(v, __shfl_xor(v, 4));
          v = fmaxf(v, __shfl_xor(v, 8));
          float mn = fmaxf(mst[mt][r], v);
          al[mt][r] = __expf(mst[mt][r] - mn);
          mst[mt][r] = mn;
        }
#pragma unroll
      for (int mt = 0; mt < 2; ++mt)
#pragma unroll
        for (int r = 0; r < 4; ++r) {
          float sum = 0.f;
#pragma unroll
          for (int nt = 0; nt < 4; ++nt) {
            float p = __expf(S[mt][nt][r] - mst[mt][r]);
            S[mt][nt][r] = p;
            sum += p;
          }
          sum += __shfl_xor(sum, 1);
          sum += __shfl_xor(sum, 2);
          sum += __shfl_xor(sum, 4);
          sum += __shfl_xor(sum, 8);
          lst[mt][r] = lst[mt][r] * al[mt][r] + sum;
        }
#pragma unroll
      for (int mt = 0; mt < 2; ++mt)
#pragma unroll
        for (int nd = 0; nd < 8; ++nd)
#pragma unroll
          for (int r = 0; r < 4; ++r) O[mt][nd][r] *= al[mt][r];
      // P -> LDS (C-layout scatter; 2B stride-1-ish writes, 16B-aligned rows for A-frag reads)
      u16* Pw = Pl + w * (32 * 72);
#pragma unroll
      for (int mt = 0; mt < 2; ++mt)
#pragma unroll
        for (int nt = 0; nt < 4; ++nt)
#pragma unroll
          for (int r = 0; r < 4; ++r)
            Pw[(mt * 16 + q4 * 4 + r) * 72 + nt * 16 + m] = f2bf(S[mt][nt][r]);
      // O += P V : 32 MFMAs
#pragma unroll
      for (int k2 = 0; k2 < 2; ++k2) {
        bf16x8 ap[2];
#pragma unroll
        for (int mt = 0; mt < 2; ++mt)
          ap[mt] = *(const bf16x8*)(Pw + (mt * 16 + m) * 72 + k2 * 32 + q4 * 8);
#pragma unroll
        for (int nd = 0; nd < 8; ++nd) {
          bf16x8 bv = *(const bf16x8*)(Vt + (nd * 16 + m) * 72 + k2 * 32 + q4 * 8);
          O[0][nd] = MFMA16(ap[0], bv, O[0][nd]);
          O[1][nd] = MFMA16(ap[1], bv, O[1][nd]);
        }
      }
    }
  }

  // normalize + store
#pragma unroll
  for (int mt = 0; mt < 2; ++mt)
#pragma unroll
    for (int r = 0; r < 4; ++r) {
      float il = 1.0f / lst[mt][r];
      int row = soff + qtl * 128 + w * 32 + mt * 16 + q4 * 4 + r;
      u16* op = attn + (size_t)row * HID + n * HDIM + m;
#pragma unroll
      for (int nd = 0; nd < 8; ++nd)
        op[nd * 16] = f2bf(O[mt][nd][r] * il);
    }
}

// ---------------- paged decode attention ----------------
// grid: (32 decode tokens, 8 kv heads); block 256. RoPE applied on the fly to cached keys.
__global__ __launch_bounds__(256) void decode_attn(const u16* __restrict__ qb, const u16* __restrict__ kb,
                                                   const u16* __restrict__ vb,
                                                   const float* __restrict__ cacheK,
                                                   const float* __restrict__ cacheV,
                                                   const float* __restrict__ tcos,
                                                   const float* __restrict__ tsin,
                                                   u16* __restrict__ attn) {
  const int d = blockIdx.x, h = blockIdx.y;
  const int tid = threadIdx.x;
  const int w = tid >> 6;

  __shared__ float qs[4][128];
  __shared__ float sl[4][2064];
  __shared__ float red[2][4][4];
  __shared__ float obuf[2][4][128];

  for (int i = tid; i < 512; i += 256) {
    int g = i >> 7, c = i & 127;
    qs[g][c] = bf2f(qb[(size_t)(D_OFF + d) * HID + (h * 4 + g) * HDIM + c]) * SCALE_F;
  }
  __syncthreads();

  float sc[9][4];
  float lmax[4] = {-3.0e38f, -3.0e38f, -3.0e38f, -3.0e38f};
  int kk = 0;
  for (int t = tid; t <= PASTLEN; t += 256, ++kk) {
    float a0 = 0.f, a1 = 0.f, a2 = 0.f, a3 = 0.f;
    if (t < PASTLEN) {
      const float* kr = cacheK + (((size_t)d * PASTLEN + t) * NKVH + h) * HDIM;
      const float* tcp = tcos + (size_t)t * 64;
      const float* tsp = tsin + (size_t)t * 64;
      for (int i = 0; i < 64; i += 4) {
        float ka[4], kb4[4], cc[4], sn[4];
        *(float4*)ka  = *(const float4*)(kr + i);
        *(float4*)kb4 = *(const float4*)(kr + 64 + i);
        *(float4*)cc  = *(const float4*)(tcp + i);
        *(float4*)sn  = *(const float4*)(tsp + i);
#pragma unroll
        for (int c = 0; c < 4; ++c) {
          float lo = ka[c] * cc[c] - kb4[c] * sn[c];
          float hi = kb4[c] * cc[c] + ka[c] * sn[c];
          a0 += lo * qs[0][i + c] + hi * qs[0][64 + i + c];
          a1 += lo * qs[1][i + c] + hi * qs[1][64 + i + c];
          a2 += lo * qs[2][i + c] + hi * qs[2][64 + i + c];
          a3 += lo * qs[3][i + c] + hi * qs[3][64 + i + c];
        }
      }
    } else {
      // t == PASTLEN: freshly-projected decode key, already roped at pos 2048
      const u16* kr = kb + (size_t)(D_OFF + d) * (NKVH * HDIM) + h * HDIM;
      for (int i = 0; i < 128; ++i) {
        float kf = bf2f(kr[i]);
        a0 += kf * qs[0][i]; a1 += kf * qs[1][i];
        a2 += kf * qs[2][i]; a3 += kf * qs[3][i];
      }
    }
    sc[kk][0] = a0; sc[kk][1] = a1; sc[kk][2] = a2; sc[kk][3] = a3;
    lmax[0] = fmaxf(lmax[0], a0); lmax[1] = fmaxf(lmax[1], a1);
    lmax[2] = fmaxf(lmax[2], a2); lmax[3] = fmaxf(lmax[3], a3);
  }
#pragma unroll
  for (int g = 0; g < 4; ++g)
    for (int msk = 1; msk <= 32; msk <<= 1)
      lmax[g] = fmaxf(lmax[g], __shfl_xor(lmax[g], msk));
  if ((tid & 63) == 0)
#pragma unroll
    for (int g = 0; g < 4; ++g) red[0][w][g] = lmax[g];
  __syncthreads();
  float gmax[4], lsum[4] = {0.f, 0.f, 0.f, 0.f};
#pragma unroll
  for (int g = 0; g < 4; ++g)
    gmax[g] = fmaxf(fmaxf(red[0][0][g], red[0][1][g]), fmaxf(red[0][2][g], red[0][3][g]));
  kk = 0;
  for (int t = tid; t <= PASTLEN; t += 256, ++kk) {
#pragma unroll
    for (int g = 0; g < 4; ++g) {
      float p = __expf(sc[kk][g] - gmax[g]);
      sl[g][t] = p;
      lsum[g] += p;
    }
  }
#pragma unroll
  for (int g = 0; g < 4; ++g)
    for (int msk = 1; msk <= 32; msk <<= 1)
      lsum[g] += __shfl_xor(lsum[g], msk);
  if ((tid & 63) == 0)
#pragma unroll
    for (int g = 0; g < 4; ++g) red[1][w][g] = lsum[g];
  __syncthreads();
  float gsum[4];
#pragma unroll
  for (int g = 0; g < 4; ++g)
    gsum[g] = red[1][0][g] + red[1][1][g] + red[1][2][g] + red[1][3][g];

  // pass 2: O = P V
  const int tp = tid >> 7, ii = tid & 127;
  float acc4[4] = {0.f, 0.f, 0.f, 0.f};
  for (int t = tp; t <= PASTLEN; t += 2) {
    float v;
    if (t < PASTLEN) v = cacheV[(((size_t)d * PASTLEN + t) * NKVH + h) * HDIM + ii];
    else             v = bf2f(vb[(size_t)(D_OFF + d) * (NKVH * HDIM) + h * HDIM + ii]);
#pragma unroll
    for (int g = 0; g < 4; ++g) acc4[g] += sl[g][t] * v;
  }
#pragma unroll
  for (int g = 0; g < 4; ++g) obuf[tp][g][ii] = acc4[g];
  __syncthreads();
  for (int i = tid; i < 512; i += 256) {
    int g = i >> 7, c = i & 127;
    float o = (obuf[0][g][c] + obuf[1][g][c]) / gsum[g];
    attn[(size_t)(D_OFF + d) * HID + (h * 4 + g) * HDIM + c] = f2bf(o);
  }
}

// ---------------- host launcher ----------------
extern "C" void kernel_launch(void* const* d_in, const int* in_sizes, int n_in,
                              void* d_out, int out_size, void* d_ws, size_t ws_size,
                              hipStream_t stream) {
  const float* hs = (const float*)d_in[0];
  const float* wq = (const float*)d_in[1];
  const float* wk = (const float*)d_in[2];
  const float* wv = (const float*)d_in[3];
  const float* wo = (const float*)d_in[4];
  const float* ck = (const float*)d_in[5];
  const float* cv = (const float*)d_in[6];
  float* out = (float*)d_out;

  char* ws = (char*)d_ws;
  size_t off = 0;
  auto alloc = [&](size_t bytes) -> void* {
    void* p = ws + off;
    off += (bytes + 255) & ~(size_t)255;
    return p;
  };
  // ~224 MB total workspace
  u16* hb   = (u16*)alloc((size_t)T_PAD * HID * 2);
  u16* qbuf = (u16*)alloc((size_t)T_PAD * HID * 2);
  u16* kbuf = (u16*)alloc((size_t)T_PAD * NKVH * HDIM * 2);
  u16* vbuf = (u16*)alloc((size_t)T_PAD * NKVH * HDIM * 2);
  u16* atn  = (u16*)alloc((size_t)T_PAD * HID * 2);
  u16* wqb  = (u16*)alloc((size_t)HID * HID * 2);
  u16* wkb  = (u16*)alloc((size_t)NKVH * HDIM * HID * 2);
  u16* wvb  = (u16*)alloc((size_t)NKVH * HDIM * HID * 2);
  u16* wob  = (u16*)alloc((size_t)HID * HID * 2);
  float* tc = (float*)alloc((size_t)(PASTLEN + 1) * 64 * 4);
  float* tsn = (float*)alloc((size_t)(PASTLEN + 1) * 64 * 4);

  // 1. casts
  cast_pad_hidden<<<(T_PAD * HID / 8) / 256, 256, 0, stream>>>(hs, hb);
  cast_w<<<(HID * HID / 8 + 255) / 256, 256, 0, stream>>>(wq, wqb, HID * HID / 8);
  cast_w<<<(NKVH * HDIM * HID / 8 + 255) / 256, 256, 0, stream>>>(wk, wkb, NKVH * HDIM * HID / 8);
  cast_w<<<(NKVH * HDIM * HID / 8 + 255) / 256, 256, 0, stream>>>(wv, wvb, NKVH * HDIM * HID / 8);
  cast_w<<<(HID * HID / 8 + 255) / 256, 256, 0, stream>>>(wo, wob, HID * HID / 8);
  rope_table<<<PASTLEN + 1, 64, 0, stream>>>(tc, tsn);

  // 2. QKV projections
  gemm_bt<u16><<<dim3(HID / 128, T_PAD / 128), 256, 0, stream>>>(hb, wqb, qbuf, HID, HID, T_PAD);
  gemm_bt<u16><<<dim3(NKVH * HDIM / 128, T_PAD / 128), 256, 0, stream>>>(hb, wkb, kbuf, NKVH * HDIM, HID, T_PAD);
  gemm_bt<u16><<<dim3(NKVH * HDIM / 128, T_PAD / 128), 256, 0, stream>>>(hb, wvb, vbuf, NKVH * HDIM, HID, T_PAD);

  // 3. RoPE on q and k (prefill: seq-local pos; decode rows: pos 2048)
  rope_apply<<<T_TOT, 256, 0, stream>>>(qbuf, kbuf, tc, tsn);

  // 4. attention
  flash_prefill<<<dim3(40, NQH), 256, 0, stream>>>(qbuf, kbuf, vbuf, atn);
  decode_attn<<<dim3(N_DEC, NKVH), 256, 0, stream>>>(qbuf, kbuf, vbuf, ck, cv, tc, tsn, atn);

  // 5. output projection -> fp32 d_out (rows < T_TOT)
  gemm_bt<float><<<dim3(HID / 128, T_PAD / 128), 256, 0, stream>>>(atn, wob, out, HID, HID, T_TOT);

  (void)in_sizes; (void)n_in; (void)out_size; (void)ws_size;
}

// Round 2
// 2042.719 us; speedup vs baseline: 1.9724x; 1.9724x over previous
//
#include <hip/hip_runtime.h>
#include <stdint.h>
#include <stddef.h>

// ---------------- problem constants ----------------
#define T_TOT   5152            // DOFF + DECODE
#define T_PAD   5248            // 41 * 128
#define D_OFF   5120
#define N_DEC   32
#define PASTLEN 2048
#define HID     4096
#define NQH     32
#define NKVH    8
#define HDIM    128
#define KVS     2048            // combined K|V row stride (k: cols 0..1023, v: 1024..2047)
#define SCALE_F 0.088388347648318447f   // 1/sqrt(128)

typedef unsigned short u16;
typedef __attribute__((ext_vector_type(8))) short bf16x8;   // 8 bf16 = 4 VGPRs (MFMA A/B frag)
typedef __attribute__((ext_vector_type(4))) float f32x4;    // MFMA C/D frag

#define MFMA16(a, b, c) __builtin_amdgcn_mfma_f32_16x16x32_bf16((a), (b), (c), 0, 0, 0)

__device__ __forceinline__ float bf2f(u16 h) { return __uint_as_float(((unsigned)h) << 16); }
__device__ __forceinline__ u16 f2bf(float f) {
  unsigned u = __float_as_uint(f);
  return (u16)((u + 0x7FFFu + ((u >> 16) & 1u)) >> 16);   // RNE
}

// async global->LDS, 16B per lane; LDS dest = wave-uniform base + lane*16
__device__ __forceinline__ void async_ld16(const u16* g, u16* l) {
  __builtin_amdgcn_global_load_lds((const __attribute__((address_space(1))) void*)g,
                                   (__attribute__((address_space(3))) void*)l,
                                   16, 0, 0);
}

// ---------------- cast kernels ----------------
// hidden [T_TOT][HID] fp32 -> [T_PAD][HID] bf16, zero-filled pad rows
__global__ void cast_pad_hidden(const float* __restrict__ src, u16* __restrict__ dst) {
  long idx = ((long)blockIdx.x * 256 + threadIdx.x) * 8;
  int row = (int)(idx >> 12);
  __align__(16) u16 tmp[8];
  if (row < T_TOT) {
    const float4* s = (const float4*)(src + (size_t)row * HID + (idx & 4095));
    float4 a = s[0], b = s[1];
    tmp[0] = f2bf(a.x); tmp[1] = f2bf(a.y); tmp[2] = f2bf(a.z); tmp[3] = f2bf(a.w);
    tmp[4] = f2bf(b.x); tmp[5] = f2bf(b.y); tmp[6] = f2bf(b.z); tmp[7] = f2bf(b.w);
  } else {
#pragma unroll
    for (int j = 0; j < 8; ++j) tmp[j] = 0;
  }
  *(uint4*)(dst + idx) = *(const uint4*)tmp;
}

__global__ void cast_w(const float* __restrict__ src, u16* __restrict__ dst, int n8) {
  int i = blockIdx.x * 256 + threadIdx.x;
  if (i >= n8) return;
  long idx = (long)i * 8;
  const float4* s = (const float4*)(src + idx);
  float4 a = s[0], b = s[1];
  __align__(16) u16 tmp[8];
  tmp[0] = f2bf(a.x); tmp[1] = f2bf(a.y); tmp[2] = f2bf(a.z); tmp[3] = f2bf(a.w);
  tmp[4] = f2bf(b.x); tmp[5] = f2bf(b.y); tmp[6] = f2bf(b.z); tmp[7] = f2bf(b.w);
  *(uint4*)(dst + idx) = *(const uint4*)tmp;
}

// ---------------- RoPE ----------------
__global__ void rope_table(float* __restrict__ tcos, float* __restrict__ tsin) {
  int p = blockIdx.x;        // 0..2048
  int i = threadIdx.x;       // 0..63
  float inv = powf(10000.0f, -((float)i) / 64.0f);
  float ang = (float)p * inv;
  tcos[p * 64 + i] = cosf(ang);
  tsin[p * 64 + i] = sinf(ang);
}

// in-place RoPE on q (32 heads) and k (8 heads, in combined KV buffer)
__global__ void rope_apply(u16* __restrict__ qb, u16* __restrict__ kvb,
                           const float* __restrict__ tcos, const float* __restrict__ tsin) {
  int row = blockIdx.x;      // 0..T_TOT-1
  int pos;
  if (row >= D_OFF)      pos = PASTLEN;
  else if (row >= 4608)  pos = row - 4608;
  else if (row >= 2560)  pos = row - 2560;
  else if (row >= 1024)  pos = row - 1024;
  else                   pos = row;
  const float* tc = tcos + (size_t)pos * 64;
  const float* ts = tsin + (size_t)pos * 64;
  for (int it = threadIdx.x; it < (NQH + NKVH) * 64; it += 256) {
    int h = it >> 6, i = it & 63;
    u16* base;
    if (h < NQH) base = qb + (size_t)row * HID + h * HDIM + i;
    else         base = kvb + (size_t)row * KVS + (h - NQH) * HDIM + i;
    float x0 = bf2f(base[0]), x1 = bf2f(base[64]);
    float c = tc[i], s = ts[i];
    base[0]  = f2bf(x0 * c - x1 * s);
    base[64] = f2bf(x1 * c + x0 * s);
  }
}

// ---------------- GEMM: C[M][N] = A[M][K] * B[N][K]^T  (both bf16, K-major) ----------------
// 128x128 tile, BK=64, 256 threads = 4 waves (2x2), 4x4 16x16x32 MFMAs per wave.
// Staging via global_load_lds width=16, XOR swizzle applied on the GLOBAL side so the
// forced LDS layout (wave base + lane*16) ends up swizzled -> conflict-free ds_read_b128.
__device__ __forceinline__ void store_c(u16* p, float v)   { *p = f2bf(v); }
__device__ __forceinline__ void store_c(float* p, float v) { *p = v; }

template <typename OutT>
__global__ __launch_bounds__(256, 3) void gemm_bt(const u16* __restrict__ A, const u16* __restrict__ B,
                                                  OutT* __restrict__ C, int N, int K, int Mstore) {
  __shared__ u16 As[128 * 64];
  __shared__ u16 Bs[128 * 64];
  const int tid = threadIdx.x;
  const int lane = tid & 63, w = tid >> 6;
  const int wm = w >> 1, wn = w & 1;
  const int m = lane & 15, q4 = lane >> 4;
  const long by = blockIdx.y, bx = blockIdx.x;

  // staging: lane l covers row (base + l/8), slot (l&7); global chunk fetched = slot ^ (row&7)
  const int srow = lane >> 3;               // 0..7
  const int schunk = (lane & 7) ^ srow;     // row&7 == srow (8-row groups are 8-aligned)
  const u16* Ag = A + (by * 128 + w * 32 + srow) * (size_t)K + schunk * 8;
  const u16* Bg = B + (bx * 128 + w * 32 + srow) * (size_t)K + schunk * 8;
  u16* AsW = As + w * 32 * 64;
  u16* BsW = Bs + w * 32 * 64;

  f32x4 acc[4][4];
#pragma unroll
  for (int i = 0; i < 4; ++i)
#pragma unroll
    for (int j = 0; j < 4; ++j) acc[i][j] = (f32x4){0.f, 0.f, 0.f, 0.f};

  const int nk = K / 64;
  for (int kt = 0; kt < nk; ++kt) {
    const size_t ko = (size_t)kt * 64;
    __syncthreads();                         // prev iter's reads done before overwrite
#pragma unroll
    for (int i = 0; i < 4; ++i) {
      async_ld16(Ag + i * 8 * (size_t)K + ko, AsW + i * 8 * 64);
      async_ld16(Bg + i * 8 * (size_t)K + ko, BsW + i * 8 * 64);
    }
    __syncthreads();                         // compiler drains vmcnt(0) before barrier
#pragma unroll
    for (int ks = 0; ks < 2; ++ks) {
      bf16x8 af[4], bfr[4];
#pragma unroll
      for (int mt = 0; mt < 4; ++mt) {
        int r = wm * 64 + mt * 16 + m;
        int ch = (ks * 4 + q4) ^ (r & 7);
        af[mt] = *(const bf16x8*)(As + r * 64 + (ch << 3));
      }
#pragma unroll
      for (int nt = 0; nt < 4; ++nt) {
        int r = wn * 64 + nt * 16 + m;
        int ch = (ks * 4 + q4) ^ (r & 7);
        bfr[nt] = *(const bf16x8*)(Bs + r * 64 + (ch << 3));
      }
#pragma unroll
      for (int mt = 0; mt < 4; ++mt)
#pragma unroll
        for (int nt = 0; nt < 4; ++nt)
          acc[mt][nt] = MFMA16(af[mt], bfr[nt], acc[mt][nt]);
    }
  }

  // epilogue: C/D layout col = lane&15, row = quad*4 + reg
#pragma unroll
  for (int mt = 0; mt < 4; ++mt)
#pragma unroll
    for (int nt = 0; nt < 4; ++nt) {
      int row0 = (int)by * 128 + wm * 64 + mt * 16 + q4 * 4;
      int col = (int)bx * 128 + wn * 64 + nt * 16 + m;
#pragma unroll
      for (int r = 0; r < 4; ++r) {
        int row = row0 + r;
        if (row < Mstore) store_c(C + (size_t)row * N + col, acc[mt][nt][r]);
      }
    }
}

// ---------------- flash prefill attention ----------------
// grid: x = global q-tile (40 tiles of 128 rows), y = q head (32).
__global__ __launch_bounds__(256) void flash_prefill(const u16* __restrict__ qb,
                                                     const u16* __restrict__ kb,
                                                     const u16* __restrict__ vb,
                                                     u16* __restrict__ attn) {
  const int gq = blockIdx.x;
  const int n = blockIdx.y;
  int qtl, soff;
  if (gq < 8)       { qtl = gq;      soff = 0; }
  else if (gq < 20) { qtl = gq - 8;  soff = 1024; }
  else if (gq < 36) { qtl = gq - 20; soff = 2560; }
  else              { qtl = gq - 36; soff = 4608; }
  const int kvh = n >> 2;
  const int tid = threadIdx.x;
  const int lane = tid & 63;
  const int w = tid >> 6;
  const int m = lane & 15, q4 = lane >> 4;

  __shared__ u16 Ks[64 * 128];     // [t][d], d XOR-swizzled in 8-elem chunks
  __shared__ u16 Vt[128 * 72];     // [d][t], padded stride 72
  __shared__ u16 Pl[4 * 32 * 72];  // per-wave P [32 qr][64 t], stride 72

  bf16x8 aq[2][4];
#pragma unroll
  for (int mt = 0; mt < 2; ++mt)
#pragma unroll
    for (int ks = 0; ks < 4; ++ks) {
      int row = soff + qtl * 128 + w * 32 + mt * 16 + m;
      aq[mt][ks] = *(const bf16x8*)(qb + (size_t)row * HID + n * HDIM + ks * 32 + q4 * 8);
    }

  f32x4 O[2][8];
#pragma unroll
  for (int mt = 0; mt < 2; ++mt)
#pragma unroll
    for (int nd = 0; nd < 8; ++nd) O[mt][nd] = (f32x4){0.f, 0.f, 0.f, 0.f};
  float mst[2][4], lst[2][4];
#pragma unroll
  for (int mt = 0; mt < 2; ++mt)
#pragma unroll
    for (int r = 0; r < 4; ++r) { mst[mt][r] = -3.0e38f; lst[mt][r] = 0.f; }

  const int st_t = tid & 63;
  const int st_c = tid >> 6;
  const int ktmax = 2 * qtl + 1;

  for (int kt = 0; kt <= ktmax; ++kt) {
    __syncthreads();
    {
      const int koff = soff + kt * 64;
      const size_t gbase = (size_t)(koff + st_t) * KVS + kvh * HDIM;
#pragma unroll
      for (int p = 0; p < 4; ++p) {
        int c = st_c + p * 4;      // 0..15
        uint4 kv_ = *(const uint4*)(kb + gbase + c * 8);
        *(uint4*)(Ks + st_t * 128 + ((c ^ (st_t & 7)) << 3)) = kv_;
        union { uint4 u; u16 s[8]; } uv;
        uv.u = *(const uint4*)(vb + gbase + c * 8);
#pragma unroll
        for (int j = 0; j < 8; ++j) Vt[(c * 8 + j) * 72 + st_t] = uv.s[j];
      }
    }
    __syncthreads();

    bool skip = (kt == 2 * qtl + 1) && (w < 2);
    if (!skip) {
      f32x4 S[2][4];
#pragma unroll
      for (int mt = 0; mt < 2; ++mt)
#pragma unroll
        for (int nt = 0; nt < 4; ++nt) S[mt][nt] = (f32x4){0.f, 0.f, 0.f, 0.f};
#pragma unroll
      for (int ks = 0; ks < 4; ++ks) {
        bf16x8 bk[4];
#pragma unroll
        for (int nt = 0; nt < 4; ++nt) {
          int tr = nt * 16 + m;
          int ch = (ks * 4 + q4) ^ (tr & 7);
          bk[nt] = *(const bf16x8*)(Ks + tr * 128 + (ch << 3));
        }
#pragma unroll
        for (int mt = 0; mt < 2; ++mt)
#pragma unroll
          for (int nt = 0; nt < 4; ++nt)
            S[mt][nt] = MFMA16(aq[mt][ks], bk[nt], S[mt][nt]);
      }
#pragma unroll
      for (int mt = 0; mt < 2; ++mt)
#pragma unroll
        for (int nt = 0; nt < 4; ++nt)
#pragma unroll
          for (int r = 0; r < 4; ++r) S[mt][nt][r] *= SCALE_F;
      if (kt >= 2 * qtl) {
#pragma unroll
        for (int mt = 0; mt < 2; ++mt)
#pragma unroll
          for (int nt = 0; nt < 4; ++nt)
#pragma unroll
            for (int r = 0; r < 4; ++r) {
              int key = kt * 64 + nt * 16 + m;
              int qp = qtl * 128 + w * 32 + mt * 16 + q4 * 4 + r;
              if (key > qp) S[mt][nt][r] = -1.0e30f;
            }
      }
      float al[2][4];
#pragma unroll
      for (int mt = 0; mt < 2; ++mt)
#pragma unroll
        for (int r = 0; r < 4; ++r) {
          float v = fmaxf(fmaxf(S[mt][0][r], S[mt][1][r]), fmaxf(S[mt][2][r], S[mt][3][r]));
          v = fmaxf(v, __shfl_xor(v, 1));
          v = fmaxf(v, __shfl_xor(v, 2));
          v = fmaxf(v, __shfl_xor(v, 4));
          v = fmaxf(v, __shfl_xor(v, 8));
          float mn = fmaxf(mst[mt][r], v);
          al[mt][r] = __expf(mst[mt][r] - mn);
          mst[mt][r] = mn;
        }
#pragma unroll
      for (int mt = 0; mt < 2; ++mt)
#pragma unroll
        for (int r = 0; r < 4; ++r) {
          float sum = 0.f;
#pragma unroll
          for (int nt = 0; nt < 4; ++nt) {
            float p = __expf(S[mt][nt][r] - mst[mt][r]);
            S[mt][nt][r] = p;
            sum += p;
          }
          sum += __shfl_xor(sum, 1);
          sum += __shfl_xor(sum, 2);
          sum += __shfl_xor(sum, 4);
          sum += __shfl_xor(sum, 8);
          lst[mt][r] = lst[mt][r] * al[mt][r] + sum;
        }
#pragma unroll
      for (int mt = 0; mt < 2; ++mt)
#pragma unroll
        for (int nd = 0; nd < 8; ++nd)
#pragma unroll
          for (int r = 0; r < 4; ++r) O[mt][nd][r] *= al[mt][r];
      u16* Pw = Pl + w * (32 * 72);
#pragma unroll
      for (int mt = 0; mt < 2; ++mt)
#pragma unroll
        for (int nt = 0; nt < 4; ++nt)
#pragma unroll
          for (int r = 0; r < 4; ++r)
            Pw[(mt * 16 + q4 * 4 + r) * 72 + nt * 16 + m] = f2bf(S[mt][nt][r]);
#pragma unroll
      for (int k2 = 0; k2 < 2; ++k2) {
        bf16x8 ap[2];
#pragma unroll
        for (int mt = 0; mt < 2; ++mt)
          ap[mt] = *(const bf16x8*)(Pw + (mt * 16 + m) * 72 + k2 * 32 + q4 * 8);
#pragma unroll
        for (int nd = 0; nd < 8; ++nd) {
          bf16x8 bv = *(const bf16x8*)(Vt + (nd * 16 + m) * 72 + k2 * 32 + q4 * 8);
          O[0][nd] = MFMA16(ap[0], bv, O[0][nd]);
          O[1][nd] = MFMA16(ap[1], bv, O[1][nd]);
        }
      }
    }
  }

#pragma unroll
  for (int mt = 0; mt < 2; ++mt)
#pragma unroll
    for (int r = 0; r < 4; ++r) {
      float il = 1.0f / lst[mt][r];
      int row = soff + qtl * 128 + w * 32 + mt * 16 + q4 * 4 + r;
      u16* op = attn + (size_t)row * HID + n * HDIM + m;
#pragma unroll
      for (int nd = 0; nd < 8; ++nd)
        op[nd * 16] = f2bf(O[mt][nd][r] * il);
    }
}

// ---------------- paged decode attention ----------------
__global__ __launch_bounds__(256) void decode_attn(const u16* __restrict__ qb, const u16* __restrict__ kvb,
                                                   const float* __restrict__ cacheK,
                                                   const float* __restrict__ cacheV,
                                                   const float* __restrict__ tcos,
                                                   const float* __restrict__ tsin,
                                                   u16* __restrict__ attn) {
  const int d = blockIdx.x, h = blockIdx.y;
  const int tid = threadIdx.x;
  const int w = tid >> 6;

  __shared__ float qs[4][128];
  __shared__ float sl[4][2064];
  __shared__ float red[2][4][4];
  __shared__ float obuf[2][4][128];

  for (int i = tid; i < 512; i += 256) {
    int g = i >> 7, c = i & 127;
    qs[g][c] = bf2f(qb[(size_t)(D_OFF + d) * HID + (h * 4 + g) * HDIM + c]) * SCALE_F;
  }
  __syncthreads();

  float sc[9][4];
  float lmax[4] = {-3.0e38f, -3.0e38f, -3.0e38f, -3.0e38f};
  int kk = 0;
  for (int t = tid; t <= PASTLEN; t += 256, ++kk) {
    float a0 = 0.f, a1 = 0.f, a2 = 0.f, a3 = 0.f;
    if (t < PASTLEN) {
      const float* kr = cacheK + (((size_t)d * PASTLEN + t) * NKVH + h) * HDIM;
      const float* tcp = tcos + (size_t)t * 64;
      const float* tsp = tsin + (size_t)t * 64;
      for (int i = 0; i < 64; i += 4) {
        float ka[4], kb4[4], cc[4], sn[4];
        *(float4*)ka  = *(const float4*)(kr + i);
        *(float4*)kb4 = *(const float4*)(kr + 64 + i);
        *(float4*)cc  = *(const float4*)(tcp + i);
        *(float4*)sn  = *(const float4*)(tsp + i);
#pragma unroll
        for (int c = 0; c < 4; ++c) {
          float lo = ka[c] * cc[c] - kb4[c] * sn[c];
          float hi = kb4[c] * cc[c] + ka[c] * sn[c];
          a0 += lo * qs[0][i + c] + hi * qs[0][64 + i + c];
          a1 += lo * qs[1][i + c] + hi * qs[1][64 + i + c];
          a2 += lo * qs[2][i + c] + hi * qs[2][64 + i + c];
          a3 += lo * qs[3][i + c] + hi * qs[3][64 + i + c];
        }
      }
    } else {
      const u16* kr = kvb + (size_t)(D_OFF + d) * KVS + h * HDIM;
      for (int i = 0; i < 128; ++i) {
        float kf = bf2f(kr[i]);
        a0 += kf * qs[0][i]; a1 += kf * qs[1][i];
        a2 += kf * qs[2][i]; a3 += kf * qs[3][i];
      }
    }
    sc[kk][0] = a0; sc[kk][1] = a1; sc[kk][2] = a2; sc[kk][3] = a3;
    lmax[0] = fmaxf(lmax[0], a0); lmax[1] = fmaxf(lmax[1], a1);
    lmax[2] = fmaxf(lmax[2], a2); lmax[3] = fmaxf(lmax[3], a3);
  }
#pragma unroll
  for (int g = 0; g < 4; ++g)
    for (int msk = 1; msk <= 32; msk <<= 1)
      lmax[g] = fmaxf(lmax[g], __shfl_xor(lmax[g], msk));
  if ((tid & 63) == 0)
#pragma unroll
    for (int g = 0; g < 4; ++g) red[0][w][g] = lmax[g];
  __syncthreads();
  float gmax[4], lsum[4] = {0.f, 0.f, 0.f, 0.f};
#pragma unroll
  for (int g = 0; g < 4; ++g)
    gmax[g] = fmaxf(fmaxf(red[0][0][g], red[0][1][g]), fmaxf(red[0][2][g], red[0][3][g]));
  kk = 0;
  for (int t = tid; t <= PASTLEN; t += 256, ++kk) {
#pragma unroll
    for (int g = 0; g < 4; ++g) {
      float p = __expf(sc[kk][g] - gmax[g]);
      sl[g][t] = p;
      lsum[g] += p;
    }
  }
#pragma unroll
  for (int g = 0; g < 4; ++g)
    for (int msk = 1; msk <= 32; msk <<= 1)
      lsum[g] += __shfl_xor(lsum[g], msk);
  if ((tid & 63) == 0)
#pragma unroll
    for (int g = 0; g < 4; ++g) red[1][w][g] = lsum[g];
  __syncthreads();
  float gsum[4];
#pragma unroll
  for (int g = 0; g < 4; ++g)
    gsum[g] = red[1][0][g] + red[1][1][g] + red[1][2][g] + red[1][3][g];

  const int tp = tid >> 7, ii = tid & 127;
  float acc4[4] = {0.f, 0.f, 0.f, 0.f};
  for (int t = tp; t <= PASTLEN; t += 2) {
    float v;
    if (t < PASTLEN) v = cacheV[(((size_t)d * PASTLEN + t) * NKVH + h) * HDIM + ii];
    else             v = bf2f(kvb[(size_t)(D_OFF + d) * KVS + 1024 + h * HDIM + ii]);
#pragma unroll
    for (int g = 0; g < 4; ++g) acc4[g] += sl[g][t] * v;
  }
#pragma unroll
  for (int g = 0; g < 4; ++g) obuf[tp][g][ii] = acc4[g];
  __syncthreads();
  for (int i = tid; i < 512; i += 256) {
    int g = i >> 7, c = i & 127;
    float o = (obuf[0][g][c] + obuf[1][g][c]) / gsum[g];
    attn[(size_t)(D_OFF + d) * HID + (h * 4 + g) * HDIM + c] = f2bf(o);
  }
}

// ---------------- host launcher ----------------
extern "C" void kernel_launch(void* const* d_in, const int* in_sizes, int n_in,
                              void* d_out, int out_size, void* d_ws, size_t ws_size,
                              hipStream_t stream) {
  const float* hs = (const float*)d_in[0];
  const float* wq = (const float*)d_in[1];
  const float* wk = (const float*)d_in[2];
  const float* wv = (const float*)d_in[3];
  const float* wo = (const float*)d_in[4];
  const float* ck = (const float*)d_in[5];
  const float* cv = (const float*)d_in[6];
  float* out = (float*)d_out;

  char* ws = (char*)d_ws;
  size_t off = 0;
  auto alloc = [&](size_t bytes) -> void* {
    void* p = ws + off;
    off += (bytes + 255) & ~(size_t)255;
    return p;
  };
  u16* hb   = (u16*)alloc((size_t)T_PAD * HID * 2);
  u16* qbuf = (u16*)alloc((size_t)T_PAD * HID * 2);
  u16* kvbuf= (u16*)alloc((size_t)T_PAD * KVS * 2);       // k cols 0..1023, v cols 1024..2047
  u16* atn  = (u16*)alloc((size_t)T_PAD * HID * 2);
  u16* wqb  = (u16*)alloc((size_t)HID * HID * 2);
  u16* wkvb = (u16*)alloc((size_t)KVS * HID * 2);         // wk rows 0..1023, wv rows 1024..2047
  u16* wob  = (u16*)alloc((size_t)HID * HID * 2);
  float* tc = (float*)alloc((size_t)(PASTLEN + 1) * 64 * 4);
  float* tsn = (float*)alloc((size_t)(PASTLEN + 1) * 64 * 4);

  // 1. casts
  cast_pad_hidden<<<(T_PAD * HID / 8) / 256, 256, 0, stream>>>(hs, hb);
  cast_w<<<(HID * HID / 8 + 255) / 256, 256, 0, stream>>>(wq, wqb, HID * HID / 8);
  cast_w<<<(NKVH * HDIM * HID / 8 + 255) / 256, 256, 0, stream>>>(wk, wkvb, NKVH * HDIM * HID / 8);
  cast_w<<<(NKVH * HDIM * HID / 8 + 255) / 256, 256, 0, stream>>>(wv, wkvb + (size_t)1024 * HID, NKVH * HDIM * HID / 8);
  cast_w<<<(HID * HID / 8 + 255) / 256, 256, 0, stream>>>(wo, wob, HID * HID / 8);
  rope_table<<<PASTLEN + 1, 64, 0, stream>>>(tc, tsn);

  // 2. projections: Q (N=4096) and fused KV (N=2048)
  gemm_bt<u16><<<dim3(HID / 128, T_PAD / 128), 256, 0, stream>>>(hb, wqb, qbuf, HID, HID, T_PAD);
  gemm_bt<u16><<<dim3(KVS / 128, T_PAD / 128), 256, 0, stream>>>(hb, wkvb, kvbuf, KVS, HID, T_PAD);

  // 3. RoPE on q and k
  rope_apply<<<T_TOT, 256, 0, stream>>>(qbuf, kvbuf, tc, tsn);

  // 4. attention
  flash_prefill<<<dim3(40, NQH), 256, 0, stream>>>(qbuf, kvbuf, kvbuf + 1024, atn);
  decode_attn<<<dim3(N_DEC, NKVH), 256, 0, stream>>>(qbuf, kvbuf, ck, cv, tc, tsn, atn);

  // 5. output projection -> fp32 d_out (rows < T_TOT)
  gemm_bt<float><<<dim3(HID / 128, T_PAD / 128), 256, 0, stream>>>(atn, wob, out, HID, HID, T_TOT);

  (void)in_sizes; (void)n_in; (void)out_size; (void)ws_size;
}